// Round 10
// baseline (128.157 us; speedup 1.0000x reference)
//
#include <hip/hip_runtime.h>
#include <stdint.h>

#define BN_EPS 1e-5f

typedef __attribute__((ext_vector_type(8))) short bf16x8;
typedef __attribute__((ext_vector_type(4))) float f32x4;

// geometry
#define B_    32
#define E_    8
#define CIN   64
#define COUT  64
#define H_    112
#define W_    112
#define HW    (H_*W_)
#define HP    114
#define WP    114
#define CI    32              // channels per chunk
#define NCHUNK 2
#define NBLK  (B_*56)         // 1792 conv blocks (2 output rows each) — PROVEN config
// xT: [b][c][hp][wp][ci] bf16, 16B-slot-swizzled: slot' = slot ^ ((wp>>1)&3)
#define XT_BC_BYTES (HP*WP*CI*2)             // 831744
#define XT_BYTES    (B_*NCHUNK*XT_BC_BYTES)  // 53231616
// ker: [b][c][s][o][i] bf16
#define KER_BC_BYTES (9*COUT*CI*2)           // 36864
#define KER_OFF     XT_BYTES
#define KER_BYTES   (B_*NCHUNK*KER_BC_BYTES) // 2359296
#define PART_OFF    (KER_OFF + KER_BYTES)    // 55590912
#define PART_BYTES  (NBLK*128*4)             // 917504
#define STATS_OFF   (PART_OFF + PART_BYTES)  // 56508416
#define CVOUT_OFF   (STATS_OFF + 512)        // 56508928 (64B aligned)
#define CVOUT_BYTES ((long)B_*COUT*HW*2)     // 51380224
#define WS_NEED_BF16 (CVOUT_OFF + CVOUT_BYTES)

static __device__ __forceinline__ unsigned short f2bf(float f) {
    unsigned int u = __float_as_uint(f);
    unsigned int r = (u + 0x7fffu + ((u >> 16) & 1u)) >> 16;
    return (unsigned short)r;
}
static __device__ __forceinline__ float bf2f(unsigned short u) {
    return __uint_as_float(((unsigned int)u) << 16);
}

static __device__ __forceinline__ void gld16(void* lds, const void* g) {
    __builtin_amdgcn_global_load_lds(
        (const __attribute__((address_space(1))) void*)g,
        (__attribute__((address_space(3))) void*)lds, 16, 0, 0);
}

// ---------------- kernel 1: prep = combine (blocks 0..255) + xform (blocks 256+) ---
__global__ __launch_bounds__(256)
void prep_kernel(const float* __restrict__ rw,
                 const float* __restrict__ experts,
                 const float* __restrict__ x,
                 char* __restrict__ ws) {
    __shared__ float lds[16 * 289];   // 18496 B (combine); xform uses 14336 B of it
    int t = threadIdx.x;

    if (blockIdx.x < 256) {
        // ------------------ combine ------------------
        int blk = blockIdx.x;         // bc*4 + oq
        int oq  = blk & 3;
        int bc  = blk >> 2;
        int c = bc & 1, b = bc >> 1;

        float w[E_];
#pragma unroll
        for (int e = 0; e < E_; e++) w[e] = rw[b * E_ + e];

#pragma unroll
        for (int k = 0; k < 18; k++) {
            int idx = k * 256 + t;        // < 4608
            int o16 = idx / 288;
            int r   = idx - o16 * 288;    // r = i32*9 + s
            long base = (long)(oq * 16 + o16) * 576 + c * 288 + r;
            float s = 0.f;
#pragma unroll
            for (int e = 0; e < E_; e++) s += w[e] * experts[(long)e * 36864 + base];
            lds[o16 * 289 + r] = s;
        }
        __syncthreads();

        char* kb = ws + (long)KER_OFF + (long)bc * KER_BC_BYTES;
        for (int u = t; u < 576; u += 256) {
            int slot = u & 3;
            int o16  = (u >> 2) & 15;
            int s    = u >> 6;
            float v[8];
#pragma unroll
            for (int j = 0; j < 8; j++) v[j] = lds[o16 * 289 + (slot * 8 + j) * 9 + s];
            uint4 p;
            p.x = (unsigned)f2bf(v[0]) | ((unsigned)f2bf(v[1]) << 16);
            p.y = (unsigned)f2bf(v[2]) | ((unsigned)f2bf(v[3]) << 16);
            p.z = (unsigned)f2bf(v[4]) | ((unsigned)f2bf(v[5]) << 16);
            p.w = (unsigned)f2bf(v[6]) | ((unsigned)f2bf(v[7]) << 16);
            *(uint4*)(kb + s * (COUT * CI * 2) + (oq * 16 + o16) * (CI * 2) + slot * 16) = p;
        }
    } else {
        // ------------------ xform ------------------
        int blk = blockIdx.x - 256;   // bc*114 + hp
        int hp  = blk % HP;
        int bc  = blk / HP;
        int c = bc & 1, b = bc >> 1;
        int h = hp - 1;
        bool border = (h < 0 || h >= H_);

        if (!border) {
            const float* src = x + ((long)(b * CIN + c * CI)) * HW + (long)h * W_;
#pragma unroll
            for (int idx = t; idx < 896; idx += 256) {   // 896 float4 = 32ch x 112w
                int ch = idx / 28, col = idx % 28;
                float4 v = *(const float4*)(src + (long)ch * HW + col * 4);
                *(float4*)&lds[ch * 112 + col * 4] = v;
            }
        }
        __syncthreads();

        char* dst = ws + (long)bc * XT_BC_BYTES + (long)hp * (WP * CI * 2);
        for (int u = t; u < 456; u += 256) {   // 114 wp x 4 slots
            int slot = u & 3, wp = u >> 2;
            int w = wp - 1;
            uint4 p = {0u, 0u, 0u, 0u};
            if (!border && w >= 0 && w < W_) {
                int ch0 = slot * 8;
                float v0 = lds[(ch0 + 0) * 112 + w], v1 = lds[(ch0 + 1) * 112 + w];
                float v2 = lds[(ch0 + 2) * 112 + w], v3 = lds[(ch0 + 3) * 112 + w];
                float v4 = lds[(ch0 + 4) * 112 + w], v5 = lds[(ch0 + 5) * 112 + w];
                float v6 = lds[(ch0 + 6) * 112 + w], v7 = lds[(ch0 + 7) * 112 + w];
                p.x = (unsigned)f2bf(v0) | ((unsigned)f2bf(v1) << 16);
                p.y = (unsigned)f2bf(v2) | ((unsigned)f2bf(v3) << 16);
                p.z = (unsigned)f2bf(v4) | ((unsigned)f2bf(v5) << 16);
                p.w = (unsigned)f2bf(v6) | ((unsigned)f2bf(v7) << 16);
            }
            int sw = slot ^ ((wp >> 1) & 3);     // bank swizzle baked into global layout
            *(uint4*)(dst + wp * 64 + sw * 16) = p;
        }
    }
}

// ---------------- kernel 2: conv via MFMA + BN partial stats -----------------------
// PROVEN round-5/6/8 structure (passed post-timing validation 3x). block = (b, rb):
// 2 output rows. 4 waves: wave w -> row h0+(w>>1), Cout-half (w&1)*32.
// A=x (M=spatial w, swizzled LDS), B=kernels hoisted to regs per chunk (one L2 wait).
// NOTE: do NOT change to 4-row/512-thread (round-9 post-timing race) and do NOT add
// a min-waves launch-bounds arg (round-7 VGPR clamp -> spill).
template<bool BF16OUT>
__global__ __launch_bounds__(256)
void conv_kernel(const char* __restrict__ ws, void* __restrict__ outp,
                 float* __restrict__ partial) {
    __shared__ uint4 xs4[1888];   // 4 rows * 114 wp * 64B = 29184 + 1024 pad = 30208
    char* xs = (char*)xs4;

    int blk = blockIdx.x;         // b*56 + rb
    int b  = blk / 56;
    int rb = blk % 56;
    int h0 = rb * 2;

    int tid  = threadIdx.x;
    int wave = tid >> 6;
    int lane = tid & 63;
    int l15  = lane & 15;
    int g    = lane >> 4;
    int row  = h0 + (wave >> 1);
    int obase = (wave & 1) * 32;
    int rhalf = wave >> 1;

    // swizzled A-read base offset per kw (mt-independent: (wp>>1)&3 with wp=mt*16+l15+kw)
    int swk[3];
#pragma unroll
    for (int kw = 0; kw < 3; kw++)
        swk[kw] = (g ^ (((l15 + kw) >> 1) & 3)) * 16 + (l15 + kw) * 64;

    f32x4 acc[7][2];
#pragma unroll
    for (int mt = 0; mt < 7; mt++)
#pragma unroll
        for (int nh = 0; nh < 2; nh++)
            acc[mt][nh] = (f32x4){0.f, 0.f, 0.f, 0.f};

    for (int c = 0; c < NCHUNK; c++) {
        int bc = b * 2 + c;
        if (c) __syncthreads();
        // stage 4 padded x rows, linear via global_load_lds
        const char* src = ws + (long)bc * XT_BC_BYTES + (long)h0 * (WP * CI * 2);
#pragma unroll
        for (int i = 0; i < 7; i++) {
            int off = i * 4096 + wave * 1024;
            gld16(xs + off, src + off + lane * 16);
        }
        if (wave == 0) {
            int off = 7 * 4096;
            gld16(xs + off, src + off + lane * 16);
        }
        // hoist ALL B-fragments for this chunk into regs (18 indep L2 loads, one wait)
        const char* kbase = ws + (long)KER_OFF + (long)bc * KER_BC_BYTES;
        bf16x8 bb[9][2];
#pragma unroll
        for (int s = 0; s < 9; s++)
#pragma unroll
            for (int nh = 0; nh < 2; nh++)
                bb[s][nh] = *(const bf16x8*)(kbase + (s * COUT + obase + nh * 16 + l15) * (CI * 2) + g * 16);
        __syncthreads();

#pragma unroll
        for (int s = 0; s < 9; s++) {
            const int kh = s / 3, kw = s % 3;
            const int base = (rhalf + kh) * (WP * 64) + swk[kw];
            bf16x8 a[7];
#pragma unroll
            for (int mt = 0; mt < 7; mt++)
                a[mt] = *(const bf16x8*)(xs + base + mt * 1024);
#pragma unroll
            for (int mt = 0; mt < 7; mt++)
#pragma unroll
                for (int nh = 0; nh < 2; nh++)
                    acc[mt][nh] = __builtin_amdgcn_mfma_f32_16x16x32_bf16(a[mt], bb[s][nh], acc[mt][nh], 0, 0, 0);
        }
    }

    // ---- epilogue: stores (w = mt*16 + g*4 + r consecutive) + stats ----
    float s1[2], s2[2];
#pragma unroll
    for (int nh = 0; nh < 2; nh++) {
        int o = obase + nh * 16 + l15;
        long base = ((long)(b * COUT + o) * H_ + row) * W_;
        s1[nh] = 0.f; s2[nh] = 0.f;
#pragma unroll
        for (int mt = 0; mt < 7; mt++) {
            if (BF16OUT) {
                unsigned short* cv = (unsigned short*)outp;
                uint2 pk;
                pk.x = (unsigned)f2bf(acc[mt][nh][0]) | ((unsigned)f2bf(acc[mt][nh][1]) << 16);
                pk.y = (unsigned)f2bf(acc[mt][nh][2]) | ((unsigned)f2bf(acc[mt][nh][3]) << 16);
                *(uint2*)(cv + base + mt * 16 + g * 4) = pk;
            } else {
                float* orow = (float*)outp + base;
                *(f32x4*)(orow + mt * 16 + g * 4) = acc[mt][nh];
            }
#pragma unroll
            for (int r = 0; r < 4; r++) {
                float v = acc[mt][nh][r];
                s1[nh] += v;
                s2[nh] += v * v;
            }
        }
        s1[nh] += __shfl_xor(s1[nh], 16, 64);
        s2[nh] += __shfl_xor(s2[nh], 16, 64);
        s1[nh] += __shfl_xor(s1[nh], 32, 64);
        s2[nh] += __shfl_xor(s2[nh], 32, 64);
    }

    __syncthreads();
    float* S = (float*)xs;        // S[wave][stat][32]
    if (g == 0) {
#pragma unroll
        for (int nh = 0; nh < 2; nh++) {
            S[wave * 64 +      nh * 16 + l15] = s1[nh];
            S[wave * 64 + 32 + nh * 16 + l15] = s2[nh];
        }
    }
    __syncthreads();
    if (tid < 128) {
        int stat = tid >> 6;
        int o    = tid & 63;
        int oh   = o >> 5;
        int o32  = o & 31;
        float v = S[oh * 64 + stat * 32 + o32] + S[(oh + 2) * 64 + stat * 32 + o32];
        partial[(long)blk * 128 + stat * 64 + o] = v;   // exclusive slot: plain store
    }
}

// ---------------- kernel 2.5: reduce partials[1792][128] -> stats[128] -------------
__global__ __launch_bounds__(1024)
void reduce_kernel(const float* __restrict__ partial, float* __restrict__ stats) {
    __shared__ float4 S[32][32];      // [j][col4], 16 KB
    const float4* p4 = (const float4*)partial;
    int col4 = threadIdx.x & 31;
    int j    = threadIdx.x >> 5;      // 0..31
    float4 s = {0.f, 0.f, 0.f, 0.f};
#pragma unroll
    for (int k = 0; k < 56; k++) {
        float4 v = p4[(long)(k * 32 + j) * 32 + col4];
        s.x += v.x; s.y += v.y; s.z += v.z; s.w += v.w;
    }
    S[j][col4] = s;
    __syncthreads();
    if (threadIdx.x < 128) {
        int c4 = threadIdx.x & 31;
        int q0 = (threadIdx.x >> 5) * 8;     // 4 groups of 8
        float4 r = {0.f, 0.f, 0.f, 0.f};
#pragma unroll
        for (int q = 0; q < 8; q++) {
            float4 v = S[q0 + q][c4];
            r.x += v.x; r.y += v.y; r.z += v.z; r.w += v.w;
        }
        S[q0 / 8][c4] = r;                   // reuse rows 0..3 (safe: all reads done)
    }
    __syncthreads();
    if (threadIdx.x < 32) {
        float4 r = {0.f, 0.f, 0.f, 0.f};
#pragma unroll
        for (int q = 0; q < 4; q++) {
            float4 v = S[q][threadIdx.x];
            r.x += v.x; r.y += v.y; r.z += v.z; r.w += v.w;
        }
        ((float4*)stats)[threadIdx.x] = r;
    }
}

// ---------------- kernel 3a: BN + ReLU6 from bf16 intermediate ---------------------
// thread handles 16 bf16 (two uint4 reads, 32B) -> four float4 writes (64B)
__global__ void bn_bf16_kernel(const unsigned short* __restrict__ cv, float* __restrict__ out,
                               const float* __restrict__ stats,
                               const float* __restrict__ gamma, const float* __restrict__ beta) {
    const float invN = 1.0f / ((float)B_ * HW);
    long i16 = (long)blockIdx.x * 256 + threadIdx.x;   // < 1605632 exactly
    int o = (int)((i16 / 784) & 63);                    // 784 = HW/16 per (b,o)
    float mean = stats[o] * invN;
    float var  = stats[COUT + o] * invN - mean * mean;
    float sc = gamma[o] * rsqrtf(var + BN_EPS);
    float sh = beta[o] - mean * sc;
    long i8 = i16 * 2;
#pragma unroll
    for (int half = 0; half < 2; half++) {
        uint4 v = ((const uint4*)cv)[i8 + half];
        float f[8];
        f[0] = bf2f((unsigned short)(v.x & 0xffff)); f[1] = bf2f((unsigned short)(v.x >> 16));
        f[2] = bf2f((unsigned short)(v.y & 0xffff)); f[3] = bf2f((unsigned short)(v.y >> 16));
        f[4] = bf2f((unsigned short)(v.z & 0xffff)); f[5] = bf2f((unsigned short)(v.z >> 16));
        f[6] = bf2f((unsigned short)(v.w & 0xffff)); f[7] = bf2f((unsigned short)(v.w >> 16));
        float4 o0, o1;
        o0.x = fminf(fmaxf(f[0] * sc + sh, 0.f), 6.f);
        o0.y = fminf(fmaxf(f[1] * sc + sh, 0.f), 6.f);
        o0.z = fminf(fmaxf(f[2] * sc + sh, 0.f), 6.f);
        o0.w = fminf(fmaxf(f[3] * sc + sh, 0.f), 6.f);
        o1.x = fminf(fmaxf(f[4] * sc + sh, 0.f), 6.f);
        o1.y = fminf(fmaxf(f[5] * sc + sh, 0.f), 6.f);
        o1.z = fminf(fmaxf(f[6] * sc + sh, 0.f), 6.f);
        o1.w = fminf(fmaxf(f[7] * sc + sh, 0.f), 6.f);
        ((float4*)out)[(i8 + half) * 2]     = o0;
        ((float4*)out)[(i8 + half) * 2 + 1] = o1;
    }
}

// ---------------- kernel 3b: BN + ReLU6 in-place fp32 (fallback) -------------------
__global__ void bn_kernel(float* __restrict__ out, const float* __restrict__ stats,
                          const float* __restrict__ gamma, const float* __restrict__ beta) {
    const float invN = 1.0f / ((float)B_ * HW);
    const long total4 = (long)B_ * COUT * HW / 4;
    for (long i4 = (long)blockIdx.x * 256 + threadIdx.x; i4 < total4;
         i4 += (long)gridDim.x * 256) {
        int o = (int)((i4 / (HW / 4)) & 63);
        float mean = stats[o] * invN;
        float var  = stats[COUT + o] * invN - mean * mean;
        float sc = gamma[o] * rsqrtf(var + BN_EPS);
        float sh = beta[o] - mean * sc;
        float4 v = ((float4*)out)[i4];
        v.x = fminf(fmaxf(v.x * sc + sh, 0.f), 6.f);
        v.y = fminf(fmaxf(v.y * sc + sh, 0.f), 6.f);
        v.z = fminf(fmaxf(v.z * sc + sh, 0.f), 6.f);
        v.w = fminf(fmaxf(v.w * sc + sh, 0.f), 6.f);
        ((float4*)out)[i4] = v;
    }
}

extern "C" void kernel_launch(void* const* d_in, const int* in_sizes, int n_in,
                              void* d_out, int out_size, void* d_ws, size_t ws_size,
                              hipStream_t stream) {
    const float* x       = (const float*)d_in[0];
    const float* rw      = (const float*)d_in[1];
    const float* experts = (const float*)d_in[2];
    const float* gamma   = (const float*)d_in[3];
    const float* beta    = (const float*)d_in[4];
    float* out = (float*)d_out;
    char*  ws  = (char*)d_ws;
    float* partial = (float*)(ws + PART_OFF);
    float* stats   = (float*)(ws + STATS_OFF);

    prep_kernel<<<256 + B_ * NCHUNK * HP, 256, 0, stream>>>(rw, experts, x, ws);

    if (ws_size >= (size_t)WS_NEED_BF16) {
        unsigned short* cv = (unsigned short*)(ws + CVOUT_OFF);
        conv_kernel<true><<<NBLK, 256, 0, stream>>>(ws, (void*)cv, partial);
        reduce_kernel<<<1, 1024, 0, stream>>>(partial, stats);
        bn_bf16_kernel<<<6272, 256, 0, stream>>>(cv, out, stats, gamma, beta);
    } else {
        conv_kernel<false><<<NBLK, 256, 0, stream>>>(ws, (void*)out, partial);
        reduce_kernel<<<1, 1024, 0, stream>>>(partial, stats);
        bn_kernel<<<4096, 256, 0, stream>>>(out, stats, gamma, beta);
    }
}

// Round 11
// 116.492 us; speedup vs baseline: 1.1001x; 1.1001x over previous
//
#include <hip/hip_runtime.h>
#include <stdint.h>

#define BN_EPS 1e-5f

typedef __attribute__((ext_vector_type(8))) short bf16x8;
typedef __attribute__((ext_vector_type(4))) float f32x4;

// geometry
#define B_    32
#define E_    8
#define CIN   64
#define COUT  64
#define H_    112
#define W_    112
#define HW    (H_*W_)
#define HP    114
#define WP    114
#define CI    32              // channels per chunk
#define NCHUNK 2
#define NBLK  (B_*56)         // 1792 conv blocks (2 output rows each) — PROVEN config
// xT: [b][c][hp][wp][ci] bf16, 16B-slot-swizzled: slot' = slot ^ ((wp>>1)&3)
#define XT_BC_BYTES (HP*WP*CI*2)             // 831744
#define XT_BYTES    (B_*NCHUNK*XT_BC_BYTES)  // 53231616
// ker: [b][c][s][o][i] bf16
#define KER_BC_BYTES (9*COUT*CI*2)           // 36864
#define KER_OFF     XT_BYTES
#define KER_BYTES   (B_*NCHUNK*KER_BC_BYTES) // 2359296
#define PART_OFF    (KER_OFF + KER_BYTES)    // 55590912
#define PART_BYTES  (NBLK*128*4)             // 917504
#define STATS_OFF   (PART_OFF + PART_BYTES)  // 56508416
#define CVOUT_OFF   (STATS_OFF + 512)        // 56508928 (64B aligned)
#define CVOUT_BYTES ((long)B_*COUT*HW*2)     // 51380224
#define WS_NEED_BF16 (CVOUT_OFF + CVOUT_BYTES)

static __device__ __forceinline__ unsigned short f2bf(float f) {
    unsigned int u = __float_as_uint(f);
    unsigned int r = (u + 0x7fffu + ((u >> 16) & 1u)) >> 16;
    return (unsigned short)r;
}
static __device__ __forceinline__ float bf2f(unsigned short u) {
    return __uint_as_float(((unsigned int)u) << 16);
}

static __device__ __forceinline__ void gld16(void* lds, const void* g) {
    __builtin_amdgcn_global_load_lds(
        (const __attribute__((address_space(1))) void*)g,
        (__attribute__((address_space(3))) void*)lds, 16, 0, 0);
}

// ---------------- kernel 1: prep = combine (blocks 0..255) + xform (blocks 256+) ---
__global__ __launch_bounds__(256)
void prep_kernel(const float* __restrict__ rw,
                 const float* __restrict__ experts,
                 const float* __restrict__ x,
                 char* __restrict__ ws) {
    __shared__ float lds[16 * 289];   // 18496 B (combine); xform uses 14336 B of it
    int t = threadIdx.x;

    if (blockIdx.x < 256) {
        // ------------------ combine ------------------
        int blk = blockIdx.x;         // bc*4 + oq
        int oq  = blk & 3;
        int bc  = blk >> 2;
        int c = bc & 1, b = bc >> 1;

        float w[E_];
#pragma unroll
        for (int e = 0; e < E_; e++) w[e] = rw[b * E_ + e];

#pragma unroll
        for (int k = 0; k < 18; k++) {
            int idx = k * 256 + t;        // < 4608
            int o16 = idx / 288;
            int r   = idx - o16 * 288;    // r = i32*9 + s
            long base = (long)(oq * 16 + o16) * 576 + c * 288 + r;
            float s = 0.f;
#pragma unroll
            for (int e = 0; e < E_; e++) s += w[e] * experts[(long)e * 36864 + base];
            lds[o16 * 289 + r] = s;
        }
        __syncthreads();

        char* kb = ws + (long)KER_OFF + (long)bc * KER_BC_BYTES;
        for (int u = t; u < 576; u += 256) {
            int slot = u & 3;
            int o16  = (u >> 2) & 15;
            int s    = u >> 6;
            float v[8];
#pragma unroll
            for (int j = 0; j < 8; j++) v[j] = lds[o16 * 289 + (slot * 8 + j) * 9 + s];
            uint4 p;
            p.x = (unsigned)f2bf(v[0]) | ((unsigned)f2bf(v[1]) << 16);
            p.y = (unsigned)f2bf(v[2]) | ((unsigned)f2bf(v[3]) << 16);
            p.z = (unsigned)f2bf(v[4]) | ((unsigned)f2bf(v[5]) << 16);
            p.w = (unsigned)f2bf(v[6]) | ((unsigned)f2bf(v[7]) << 16);
            *(uint4*)(kb + s * (COUT * CI * 2) + (oq * 16 + o16) * (CI * 2) + slot * 16) = p;
        }
    } else {
        // ------------------ xform ------------------
        int blk = blockIdx.x - 256;   // bc*114 + hp
        int hp  = blk % HP;
        int bc  = blk / HP;
        int c = bc & 1, b = bc >> 1;
        int h = hp - 1;
        bool border = (h < 0 || h >= H_);

        if (!border) {
            const float* src = x + ((long)(b * CIN + c * CI)) * HW + (long)h * W_;
#pragma unroll
            for (int idx = t; idx < 896; idx += 256) {   // 896 float4 = 32ch x 112w
                int ch = idx / 28, col = idx % 28;
                float4 v = *(const float4*)(src + (long)ch * HW + col * 4);
                *(float4*)&lds[ch * 112 + col * 4] = v;
            }
        }
        __syncthreads();

        char* dst = ws + (long)bc * XT_BC_BYTES + (long)hp * (WP * CI * 2);
        for (int u = t; u < 456; u += 256) {   // 114 wp x 4 slots
            int slot = u & 3, wp = u >> 2;
            int w = wp - 1;
            uint4 p = {0u, 0u, 0u, 0u};
            if (!border && w >= 0 && w < W_) {
                int ch0 = slot * 8;
                float v0 = lds[(ch0 + 0) * 112 + w], v1 = lds[(ch0 + 1) * 112 + w];
                float v2 = lds[(ch0 + 2) * 112 + w], v3 = lds[(ch0 + 3) * 112 + w];
                float v4 = lds[(ch0 + 4) * 112 + w], v5 = lds[(ch0 + 5) * 112 + w];
                float v6 = lds[(ch0 + 6) * 112 + w], v7 = lds[(ch0 + 7) * 112 + w];
                p.x = (unsigned)f2bf(v0) | ((unsigned)f2bf(v1) << 16);
                p.y = (unsigned)f2bf(v2) | ((unsigned)f2bf(v3) << 16);
                p.z = (unsigned)f2bf(v4) | ((unsigned)f2bf(v5) << 16);
                p.w = (unsigned)f2bf(v6) | ((unsigned)f2bf(v7) << 16);
            }
            int sw = slot ^ ((wp >> 1) & 3);     // bank swizzle baked into global layout
            *(uint4*)(dst + wp * 64 + sw * 16) = p;
        }
    }
}

// ---------------- kernel 2: conv via MFMA + BN partial stats -----------------------
// PROVEN round-5/6/8 structure. block(swizzled) = (b, rb): 2 output rows.
// 4 waves: wave w -> row h0+(w>>1), Cout-half (w&1)*32.
// XCD swizzle: 1792 = 8 XCDs x 224, and 224 = 4x56 -> each XCD owns 4 complete
// samples b (kernel + xT rows stay in its private L2; adjacent rb tiles share
// 2 of 4 staged rows).
// NOTE: do NOT change to 4-row/512-thread (round-9 post-timing race) and do NOT add
// a min-waves launch-bounds arg (round-7 VGPR clamp -> spill).
template<bool BF16OUT>
__global__ __launch_bounds__(256)
void conv_kernel(const char* __restrict__ ws, void* __restrict__ outp,
                 float* __restrict__ partial) {
    __shared__ uint4 xs4[1888];   // 4 rows * 114 wp * 64B = 29184 + 1024 pad = 30208
    char* xs = (char*)xs4;

    int blk0 = blockIdx.x;
    int blk  = (blk0 & 7) * 224 + (blk0 >> 3);   // bijective XCD swizzle (1792 = 8*224)
    int b  = blk / 56;
    int rb = blk % 56;
    int h0 = rb * 2;

    int tid  = threadIdx.x;
    int wave = tid >> 6;
    int lane = tid & 63;
    int l15  = lane & 15;
    int g    = lane >> 4;
    int row  = h0 + (wave >> 1);
    int obase = (wave & 1) * 32;
    int rhalf = wave >> 1;

    // swizzled A-read base offset per kw (mt-independent: (wp>>1)&3 with wp=mt*16+l15+kw)
    int swk[3];
#pragma unroll
    for (int kw = 0; kw < 3; kw++)
        swk[kw] = (g ^ (((l15 + kw) >> 1) & 3)) * 16 + (l15 + kw) * 64;

    f32x4 acc[7][2];
#pragma unroll
    for (int mt = 0; mt < 7; mt++)
#pragma unroll
        for (int nh = 0; nh < 2; nh++)
            acc[mt][nh] = (f32x4){0.f, 0.f, 0.f, 0.f};

    for (int c = 0; c < NCHUNK; c++) {
        int bc = b * 2 + c;
        if (c) __syncthreads();
        // stage 4 padded x rows, linear via global_load_lds
        const char* src = ws + (long)bc * XT_BC_BYTES + (long)h0 * (WP * CI * 2);
#pragma unroll
        for (int i = 0; i < 7; i++) {
            int off = i * 4096 + wave * 1024;
            gld16(xs + off, src + off + lane * 16);
        }
        if (wave == 0) {
            int off = 7 * 4096;
            gld16(xs + off, src + off + lane * 16);
        }
        // hoist ALL B-fragments for this chunk into regs (18 indep L2 loads, one wait)
        const char* kbase = ws + (long)KER_OFF + (long)bc * KER_BC_BYTES;
        bf16x8 bb[9][2];
#pragma unroll
        for (int s = 0; s < 9; s++)
#pragma unroll
            for (int nh = 0; nh < 2; nh++)
                bb[s][nh] = *(const bf16x8*)(kbase + (s * COUT + obase + nh * 16 + l15) * (CI * 2) + g * 16);
        __syncthreads();

#pragma unroll
        for (int s = 0; s < 9; s++) {
            const int kh = s / 3, kw = s % 3;
            const int base = (rhalf + kh) * (WP * 64) + swk[kw];
            bf16x8 a[7];
#pragma unroll
            for (int mt = 0; mt < 7; mt++)
                a[mt] = *(const bf16x8*)(xs + base + mt * 1024);
#pragma unroll
            for (int mt = 0; mt < 7; mt++)
#pragma unroll
                for (int nh = 0; nh < 2; nh++)
                    acc[mt][nh] = __builtin_amdgcn_mfma_f32_16x16x32_bf16(a[mt], bb[s][nh], acc[mt][nh], 0, 0, 0);
        }
    }

    // ---- epilogue: stores (w = mt*16 + g*4 + r consecutive) + stats ----
    float s1[2], s2[2];
#pragma unroll
    for (int nh = 0; nh < 2; nh++) {
        int o = obase + nh * 16 + l15;
        long base = ((long)(b * COUT + o) * H_ + row) * W_;
        s1[nh] = 0.f; s2[nh] = 0.f;
#pragma unroll
        for (int mt = 0; mt < 7; mt++) {
            if (BF16OUT) {
                unsigned short* cv = (unsigned short*)outp;
                uint2 pk;
                pk.x = (unsigned)f2bf(acc[mt][nh][0]) | ((unsigned)f2bf(acc[mt][nh][1]) << 16);
                pk.y = (unsigned)f2bf(acc[mt][nh][2]) | ((unsigned)f2bf(acc[mt][nh][3]) << 16);
                *(uint2*)(cv + base + mt * 16 + g * 4) = pk;
            } else {
                float* orow = (float*)outp + base;
                *(f32x4*)(orow + mt * 16 + g * 4) = acc[mt][nh];
            }
#pragma unroll
            for (int r = 0; r < 4; r++) {
                float v = acc[mt][nh][r];
                s1[nh] += v;
                s2[nh] += v * v;
            }
        }
        s1[nh] += __shfl_xor(s1[nh], 16, 64);
        s2[nh] += __shfl_xor(s2[nh], 16, 64);
        s1[nh] += __shfl_xor(s1[nh], 32, 64);
        s2[nh] += __shfl_xor(s2[nh], 32, 64);
    }

    __syncthreads();
    float* S = (float*)xs;        // S[wave][stat][32]
    if (g == 0) {
#pragma unroll
        for (int nh = 0; nh < 2; nh++) {
            S[wave * 64 +      nh * 16 + l15] = s1[nh];
            S[wave * 64 + 32 + nh * 16 + l15] = s2[nh];
        }
    }
    __syncthreads();
    if (tid < 128) {
        int stat = tid >> 6;
        int o    = tid & 63;
        int oh   = o >> 5;
        int o32  = o & 31;
        float v = S[oh * 64 + stat * 32 + o32] + S[(oh + 2) * 64 + stat * 32 + o32];
        partial[(long)blk * 128 + stat * 64 + o] = v;   // exclusive slot: plain store
    }
}

// ---------------- kernel 2.5: reduce partials[1792][128] -> stats[128] -------------
__global__ __launch_bounds__(1024)
void reduce_kernel(const float* __restrict__ partial, float* __restrict__ stats) {
    __shared__ float4 S[32][32];      // [j][col4], 16 KB
    const float4* p4 = (const float4*)partial;
    int col4 = threadIdx.x & 31;
    int j    = threadIdx.x >> 5;      // 0..31
    float4 s = {0.f, 0.f, 0.f, 0.f};
#pragma unroll
    for (int k = 0; k < 56; k++) {
        float4 v = p4[(long)(k * 32 + j) * 32 + col4];
        s.x += v.x; s.y += v.y; s.z += v.z; s.w += v.w;
    }
    S[j][col4] = s;
    __syncthreads();
    if (threadIdx.x < 128) {
        int c4 = threadIdx.x & 31;
        int q0 = (threadIdx.x >> 5) * 8;     // 4 groups of 8
        float4 r = {0.f, 0.f, 0.f, 0.f};
#pragma unroll
        for (int q = 0; q < 8; q++) {
            float4 v = S[q0 + q][c4];
            r.x += v.x; r.y += v.y; r.z += v.z; r.w += v.w;
        }
        S[q0 / 8][c4] = r;                   // reuse rows 0..3 (safe: all reads done)
    }
    __syncthreads();
    if (threadIdx.x < 32) {
        float4 r = {0.f, 0.f, 0.f, 0.f};
#pragma unroll
        for (int q = 0; q < 4; q++) {
            float4 v = S[q][threadIdx.x];
            r.x += v.x; r.y += v.y; r.z += v.z; r.w += v.w;
        }
        ((float4*)stats)[threadIdx.x] = r;
    }
}

// ---------------- kernel 3a: BN + ReLU6 from bf16 intermediate ---------------------
// (round-8 proven: 8 bf16/thread, one uint4 read -> two float4 writes, 12544 blocks)
__global__ void bn_bf16_kernel(const unsigned short* __restrict__ cv, float* __restrict__ out,
                               const float* __restrict__ stats,
                               const float* __restrict__ gamma, const float* __restrict__ beta) {
    const float invN = 1.0f / ((float)B_ * HW);
    long i8 = (long)blockIdx.x * 256 + threadIdx.x;   // < 3211264 exactly
    int o = (int)((i8 / (HW / 8)) & 63);
    float mean = stats[o] * invN;
    float var  = stats[COUT + o] * invN - mean * mean;
    float sc = gamma[o] * rsqrtf(var + BN_EPS);
    float sh = beta[o] - mean * sc;
    uint4 v = ((const uint4*)cv)[i8];
    float f[8];
    f[0] = bf2f((unsigned short)(v.x & 0xffff)); f[1] = bf2f((unsigned short)(v.x >> 16));
    f[2] = bf2f((unsigned short)(v.y & 0xffff)); f[3] = bf2f((unsigned short)(v.y >> 16));
    f[4] = bf2f((unsigned short)(v.z & 0xffff)); f[5] = bf2f((unsigned short)(v.z >> 16));
    f[6] = bf2f((unsigned short)(v.w & 0xffff)); f[7] = bf2f((unsigned short)(v.w >> 16));
    float4 o0, o1;
    o0.x = fminf(fmaxf(f[0] * sc + sh, 0.f), 6.f);
    o0.y = fminf(fmaxf(f[1] * sc + sh, 0.f), 6.f);
    o0.z = fminf(fmaxf(f[2] * sc + sh, 0.f), 6.f);
    o0.w = fminf(fmaxf(f[3] * sc + sh, 0.f), 6.f);
    o1.x = fminf(fmaxf(f[4] * sc + sh, 0.f), 6.f);
    o1.y = fminf(fmaxf(f[5] * sc + sh, 0.f), 6.f);
    o1.z = fminf(fmaxf(f[6] * sc + sh, 0.f), 6.f);
    o1.w = fminf(fmaxf(f[7] * sc + sh, 0.f), 6.f);
    ((float4*)out)[i8 * 2]     = o0;
    ((float4*)out)[i8 * 2 + 1] = o1;
}

// ---------------- kernel 3b: BN + ReLU6 in-place fp32 (fallback) -------------------
__global__ void bn_kernel(float* __restrict__ out, const float* __restrict__ stats,
                          const float* __restrict__ gamma, const float* __restrict__ beta) {
    const float invN = 1.0f / ((float)B_ * HW);
    const long total4 = (long)B_ * COUT * HW / 4;
    for (long i4 = (long)blockIdx.x * 256 + threadIdx.x; i4 < total4;
         i4 += (long)gridDim.x * 256) {
        int o = (int)((i4 / (HW / 4)) & 63);
        float mean = stats[o] * invN;
        float var  = stats[COUT + o] * invN - mean * mean;
        float sc = gamma[o] * rsqrtf(var + BN_EPS);
        float sh = beta[o] - mean * sc;
        float4 v = ((float4*)out)[i4];
        v.x = fminf(fmaxf(v.x * sc + sh, 0.f), 6.f);
        v.y = fminf(fmaxf(v.y * sc + sh, 0.f), 6.f);
        v.z = fminf(fmaxf(v.z * sc + sh, 0.f), 6.f);
        v.w = fminf(fmaxf(v.w * sc + sh, 0.f), 6.f);
        ((float4*)out)[i4] = v;
    }
}

extern "C" void kernel_launch(void* const* d_in, const int* in_sizes, int n_in,
                              void* d_out, int out_size, void* d_ws, size_t ws_size,
                              hipStream_t stream) {
    const float* x       = (const float*)d_in[0];
    const float* rw      = (const float*)d_in[1];
    const float* experts = (const float*)d_in[2];
    const float* gamma   = (const float*)d_in[3];
    const float* beta    = (const float*)d_in[4];
    float* out = (float*)d_out;
    char*  ws  = (char*)d_ws;
    float* partial = (float*)(ws + PART_OFF);
    float* stats   = (float*)(ws + STATS_OFF);

    prep_kernel<<<256 + B_ * NCHUNK * HP, 256, 0, stream>>>(rw, experts, x, ws);

    if (ws_size >= (size_t)WS_NEED_BF16) {
        unsigned short* cv = (unsigned short*)(ws + CVOUT_OFF);
        conv_kernel<true><<<NBLK, 256, 0, stream>>>(ws, (void*)cv, partial);
        reduce_kernel<<<1, 1024, 0, stream>>>(partial, stats);
        bn_bf16_kernel<<<12544, 256, 0, stream>>>(cv, out, stats, gamma, beta);
    } else {
        conv_kernel<false><<<NBLK, 256, 0, stream>>>(ws, (void*)out, partial);
        reduce_kernel<<<1, 1024, 0, stream>>>(partial, stats);
        bn_kernel<<<4096, 256, 0, stream>>>(out, stats, gamma, beta);
    }
}